// Round 14
// baseline (1105.702 us; speedup 1.0000x reference)
//
#include <hip/hip_runtime.h>
#include <hip/hip_bf16.h>
#include <math.h>

#define NN 100000
#define HID 128
#define EPSV 1e-5f

typedef short bf16x8 __attribute__((ext_vector_type(8)));
typedef float f32x4 __attribute__((ext_vector_type(4)));
typedef unsigned short u16;

__device__ __forceinline__ u16 f2b(float f) {       // f32 -> bf16 RNE
  unsigned u = __builtin_bit_cast(unsigned, f);
  u += 0x7FFFu + ((u >> 16) & 1u);
  return (u16)(u >> 16);
}
__device__ __forceinline__ float b2f(u16 h) {
  unsigned u = ((unsigned)h) << 16;
  return __builtin_bit_cast(float, u);
}

#define AS1(p) ((__attribute__((address_space(1))) void*)(p))
#define AS3(p) ((__attribute__((address_space(3))) void*)(p))

// ---------------- fused init: zero degree arrays, stats (both layers), cursors ----------------
static __global__ void k_init(float* __restrict__ degs, int n6,
                              int* __restrict__ cur, int nc,
                              float* __restrict__ stats, int ns) {
  int i = blockIdx.x * blockDim.x + threadIdx.x;
  if (i < n6) degs[i] = 0.f;
  if (i < nc) cur[i] = 0;
  if (i < ns) stats[i] = 0.f;
}

// ---------------- fused degree histogram over all 3 edge lists ----------------
static __global__ void k_deg_all(const int* __restrict__ seq, const int* __restrict__ knn,
                                 const int* __restrict__ dis, int E0, int E1, int E2,
                                 float* __restrict__ sOut, float* __restrict__ sIn) {
  int e = blockIdx.x * blockDim.x + threadIdx.x;
  int rel, eo;
  const int *src, *dst;
  if (e < E0)            { rel = 0; eo = e;           src = seq; dst = seq + E0; }
  else if (e < E0 + E1)  { rel = 1; eo = e - E0;      src = knn; dst = knn + E1; }
  else if (e < E0+E1+E2) { rel = 2; eo = e - E0 - E1; src = dis; dst = dis + E2; }
  else return;
  atomicAdd(&sOut[(size_t)rel * NN + src[eo]], 1.f);
  atomicAdd(&sIn[(size_t)rel * NN + dst[eo]], 1.f);
}

// ---------------- exclusive scan (two-level); scan1 computes counts inline ----------------
static __global__ void k_scan1_c(const float* __restrict__ indegRaw, int* __restrict__ out,
                                 int* __restrict__ aux, int n) {   // n = NN+1
  __shared__ int s[256];
  int t = threadIdx.x, i = blockIdx.x * 256 + t;
  int v = 0;
  if (i < NN) v = (int)(indegRaw[i] + indegRaw[NN + i] + indegRaw[2 * NN + i]);
  s[t] = v; __syncthreads();
#pragma unroll
  for (int d = 1; d < 256; d <<= 1) {
    int x = (t >= d) ? s[t - d] : 0;
    __syncthreads();
    s[t] += x;
    __syncthreads();
  }
  if (i < n) out[i] = s[t] - v;
  if (t == 255) aux[blockIdx.x] = s[255];
}

static __global__ void k_scan2(int* __restrict__ aux, int nb) {
  __shared__ int s[256];
  __shared__ int carry;
  int t = threadIdx.x;
  if (t == 0) carry = 0;
  __syncthreads();
  for (int base = 0; base < nb; base += 256) {
    int i = base + t;
    int v = (i < nb) ? aux[i] : 0;
    s[t] = v; __syncthreads();
#pragma unroll
    for (int d = 1; d < 256; d <<= 1) {
      int x = (t >= d) ? s[t - d] : 0;
      __syncthreads();
      s[t] += x;
      __syncthreads();
    }
    int excl = s[t] - v + carry;
    if (i < nb) aux[i] = excl;
    int tot = s[255];
    __syncthreads();
    if (t == 0) carry += tot;
    __syncthreads();
  }
}

static __global__ void k_scan3(int* __restrict__ out, const int* __restrict__ aux, int n) {
  int i = blockIdx.x * 256 + threadIdx.x;
  if (i < n) out[i] += aux[blockIdx.x];
}

// ---------------- fused CSR fill over all 3 edge lists: srt = (src<<2)|rel ----------------
static __global__ void k_fill_all(const int* __restrict__ seq, const int* __restrict__ knn,
                                  const int* __restrict__ dis, int E0, int E1, int E2,
                                  const int* __restrict__ off, int* __restrict__ cur,
                                  int* __restrict__ srt) {
  int e = blockIdx.x * blockDim.x + threadIdx.x;
  int rel, eo;
  const int *src, *dst;
  if (e < E0)            { rel = 0; eo = e;           src = seq; dst = seq + E0; }
  else if (e < E0 + E1)  { rel = 1; eo = e - E0;      src = knn; dst = knn + E1; }
  else if (e < E0+E1+E2) { rel = 2; eo = e - E0 - E1; src = dis; dst = dis + E2; }
  else return;
  int d = dst[eo];
  int p = off[d] + atomicAdd(&cur[d], 1);
  srt[p] = (src[eo] << 2) | rel;
}

// ---------------- fused weight convert ----------------
static __global__ void k_cvt_all(const float* __restrict__ W0, const float* __restrict__ W1,
                                 const float* __restrict__ fcW0, const float* __restrict__ fcW1,
                                 u16* __restrict__ Wt0, u16* __restrict__ Wt1,
                                 u16* __restrict__ fcWt0, u16* __restrict__ fcWt1) {
  const int N0 = 3 * 1280 * 128, N1 = 3 * 128 * 128, N2 = 128 * 128;
  int i = blockIdx.x * blockDim.x + threadIdx.x;
  if (i < N0) {                 // W0 [3][1280][128] -> Wt0 [(rel*128+c)][1280]
    int rel = i / (1280 * 128);
    int rem = i - rel * 1280 * 128;
    int k = rem >> 7, c = rem & 127;
    Wt0[((size_t)rel * 128 + c) * 1280 + k] = f2b(W0[i]);
  } else if (i < N0 + N1) {     // W1 [3][128][128] -> Wt1 [(rel*128+c)][128]
    int j = i - N0;
    int rel = j / (128 * 128);
    int rem = j - rel * 128 * 128;
    int k = rem >> 7, c = rem & 127;
    Wt1[((size_t)rel * 128 + c) * 128 + k] = f2b(W1[j]);
  } else if (i < N0 + N1 + N2) {
    int j = i - N0 - N1;
    int k = j >> 7, c = j & 127;
    fcWt0[c * 128 + k] = f2b(fcW0[j]);
  } else if (i < N0 + N1 + 2 * N2) {
    int j = i - N0 - N1 - N2;
    int k = j >> 7, c = j & 127;
    fcWt1[c * 128 + k] = f2b(fcW1[j]);
  }
}

// ---------------- 16-wave 3-buffer pipelined fused MFMA GEMM ----------------
// Y[row, c] = outdeg^-1/2 * (A[row,:] @ Wt[c,:]);  BM=128 x BN=384, BK=32.
// 16 waves (2m x 8n), wave tile 64x48 (4x3 frags) -> acc 48 regs -> <=128 regs/wave
// -> 4 waves/SIMD co-resident (vs 2 in the 8-wave version).
// PROVEN ordering (R11): per K-step  vmcnt(own stage-k+1 count) -> s_barrier ->
// STAGE(k+2) -> ds_read + MFMA.  The vmcnt BEFORE the barrier is what makes buffer-k
// landing a cross-wave guarantee (R13's barrier-first variant raced).
// Load split per stage: waves 0-7 {2xA f32, 1xB}, waves 8-15 {2xB}.
// AFFINE (layer 1): BN affine applied during the f32->bf16 cvt; ab table in LDS
// (drained with lgkmcnt(0) before the pipeline starts).
template<int K, bool AFFINE>
__global__ __launch_bounds__(1024)
void k_gemm_pipe(const float* __restrict__ Af,
                 const u16* __restrict__ Wt,     // [384][K] bf16
                 const float* __restrict__ soutRaw, // [3][NN] raw out-degrees
                 const float* __restrict__ abg,  // [256] affine (AFFINE only)
                 u16* __restrict__ Y,            // [M][384] bf16
                 int M)
{
  constexpr int A_U16 = 8192;                 // 16 KB f32 A (128 rows x 32 k)
  constexpr int B_U16 = 12288;                // 24 KB bf16 B (384 rows x 32 k)
  __shared__ u16 lds[3][A_U16 + B_U16];       // 120 KB
  __shared__ float abl[256];

  const int row0 = blockIdx.x * 128;
  const int t    = threadIdx.x;
  const int lane = t & 63;
  const int w    = t >> 6;          // 0..15
  const int wm   = w >> 3;          // 0..1
  const int wn   = w & 7;           // 0..7
  const int l15  = lane & 15, l4 = lane >> 4;
  const int kl   = l4 * 8;
  const int nk   = K / 32;

  // A staging row (waves 0-7 only): frag-block w = rows row0 + w*16 .. +16
  int arA = row0 + w * 16 + l15;  if (arA >= M) arA = M - 1;   // clamped dup read

  // B staging rows: wave w -> seg w; waves 8-15 also seg w+8 (segs 16..23)
  const u16* gbA = Wt + (size_t)(w * 16 + l15) * K + kl;
  const u16* gbB = Wt + (size_t)((w + 8) * 16 + l15) * K + kl;

  auto STAGE = [&](int buf, int k0) {
    u16* L = &lds[buf][0];
    if (w < 8) {
      const float* sa = Af + (size_t)arA * K + k0 + kl;
      __builtin_amdgcn_global_load_lds(AS1(sa),     AS3(L + w * 1024),       16, 0, 0);
      __builtin_amdgcn_global_load_lds(AS1(sa + 4), AS3(L + w * 1024 + 512), 16, 0, 0);
      __builtin_amdgcn_global_load_lds(AS1(gbA + k0), AS3(L + A_U16 + w * 512), 16, 0, 0);
    } else {
      __builtin_amdgcn_global_load_lds(AS1(gbA + k0), AS3(L + A_U16 + w * 512),       16, 0, 0);
      __builtin_amdgcn_global_load_lds(AS1(gbB + k0), AS3(L + A_U16 + (w + 8) * 512), 16, 0, 0);
    }
  };

  if constexpr (AFFINE) {
    if (t < 256) abl[t] = abg[t];
    // drain the ds_write so the step-0 barrier makes abl visible to all waves
    asm volatile("s_waitcnt lgkmcnt(0)" ::: "memory");
  }

  f32x4 acc[4][3];
#pragma unroll
  for (int m = 0; m < 4; ++m)
#pragma unroll
    for (int n = 0; n < 3; ++n) acc[m][n] = (f32x4){0.f, 0.f, 0.f, 0.f};

  // prologue: 2-deep prefetch
  STAGE(0, 0);
  if (nk > 1) STAGE(1, 32);

  for (int k = 0; k < nk; ++k) {
    // wait until buffer k landed (own loads); stage k+1 stays in flight
    if (k + 1 < nk) {
      if (w < 8) asm volatile("s_waitcnt vmcnt(3)" ::: "memory");
      else       asm volatile("s_waitcnt vmcnt(2)" ::: "memory");
    } else {
      asm volatile("s_waitcnt vmcnt(0)" ::: "memory");
    }
    __builtin_amdgcn_sched_barrier(0);
    __builtin_amdgcn_s_barrier();     // now buffer k is landed for ALL waves
    __builtin_amdgcn_sched_barrier(0);

    if (k + 2 < nk) STAGE((k + 2) % 3, (k + 2) * 32);  // target dead since step k-1

    const int cur = k % 3;
    const int k0 = k * 32;
    bf16x8 a[4], b[3];
    {
      f32x4 s1, s2, s3, s4;
      if constexpr (AFFINE) {
        s1 = *(const f32x4*)&abl[k0 + kl];
        s2 = *(const f32x4*)&abl[k0 + kl + 4];
        s3 = *(const f32x4*)&abl[128 + k0 + kl];
        s4 = *(const f32x4*)&abl[128 + k0 + kl + 4];
      }
      const float* Al = (const float*)&lds[cur][0];
#pragma unroll
      for (int m = 0; m < 4; ++m) {
        f32x4 lo = *(const f32x4*)&Al[(wm * 4 + m) * 512 + lane * 4];
        f32x4 hi = *(const f32x4*)&Al[(wm * 4 + m) * 512 + 256 + lane * 4];
        union { bf16x8 v; u16 u[8]; } q;
#pragma unroll
        for (int j = 0; j < 4; ++j) {
          float vlo = lo[j], vhi = hi[j];
          if constexpr (AFFINE) {
            vlo = fmaf(vlo, s1[j], s3[j]);
            vhi = fmaf(vhi, s2[j], s4[j]);
          }
          q.u[j]     = __builtin_bit_cast(u16, __float2bfloat16(vlo));
          q.u[4 + j] = __builtin_bit_cast(u16, __float2bfloat16(vhi));
        }
        a[m] = q.v;
      }
      const u16* Bl = &lds[cur][A_U16];
#pragma unroll
      for (int n = 0; n < 3; ++n) b[n] = *(const bf16x8*)&Bl[(wn * 3 + n) * 512 + lane * 8];
    }

#pragma unroll
    for (int m = 0; m < 4; ++m)
#pragma unroll
      for (int n = 0; n < 3; ++n)
        acc[m][n] = __builtin_amdgcn_mfma_f32_16x16x32_bf16(a[m], b[n], acc[m][n], 0, 0, 0);
  }

  // epilogue: C layout col=lane&15, row=(lane>>4)*4+reg; out-degree scale inlined rsqrt
#pragma unroll
  for (int m = 0; m < 4; ++m) {
    const int rb = row0 + wm * 64 + m * 16 + l4 * 4;
#pragma unroll
    for (int j = 0; j < 4; ++j) {
      const int row = rb + j;
      if (row < M) {
        u16* yrow = Y + (size_t)row * 384;
#pragma unroll
        for (int n = 0; n < 3; ++n) {
          const int c = wn * 48 + n * 16;
          const float sc = rsqrtf(fmaxf(soutRaw[(size_t)(c >> 7) * NN + row], 1.f));
          yrow[c + l15] = f2b(acc[m][n][j] * sc);
        }
      }
    }
  }
}

// ---------------- unified CSR gather (rel packed in tag, unroll 8, inline rsqrt) ----------------
static __global__ __launch_bounds__(256)
void k_gather(const int* __restrict__ off, const int* __restrict__ srt,
              const float* __restrict__ sinRaw, const u16* __restrict__ Y,
              const float* __restrict__ b, u16* __restrict__ acc16)
{
  int d = blockIdx.x * 4 + (threadIdx.x >> 6);
  if (d >= NN) return;
  int c = (threadIdx.x & 63) * 2;
  float v0 = b[c]     + b[128 + c]     + b[256 + c];
  float v1 = b[c + 1] + b[128 + c + 1] + b[256 + c + 1];
  const float sc0 = rsqrtf(fmaxf(sinRaw[d], 1.f));
  const float sc1 = rsqrtf(fmaxf(sinRaw[NN + d], 1.f));
  const float sc2 = rsqrtf(fmaxf(sinRaw[2 * NN + d], 1.f));
  int j0 = off[d], j1 = off[d + 1];
  int j = j0;
  for (; j + 8 <= j1; j += 8) {
    unsigned uu[8];
    int rr[8];
#pragma unroll
    for (int q = 0; q < 8; ++q) {
      int tg = srt[j + q];
      rr[q] = tg & 3;
      uu[q] = *(const unsigned*)&Y[(size_t)(tg >> 2) * 384 + (size_t)rr[q] * 128 + c];
    }
#pragma unroll
    for (int q = 0; q < 8; ++q) {
      float s = (rr[q] == 0) ? sc0 : ((rr[q] == 1) ? sc1 : sc2);
      v0 = fmaf(b2f((u16)(uu[q] & 0xFFFFu)), s, v0);
      v1 = fmaf(b2f((u16)(uu[q] >> 16)), s, v1);
    }
  }
  for (; j < j1; ++j) {
    int tg = srt[j];
    int r = tg & 3;
    unsigned u = *(const unsigned*)&Y[(size_t)(tg >> 2) * 384 + (size_t)r * 128 + c];
    float s = (r == 0) ? sc0 : ((r == 1) ? sc1 : sc2);
    v0 = fmaf(b2f((u16)(u & 0xFFFFu)), s, v0);
    v1 = fmaf(b2f((u16)(u >> 16)), s, v1);
  }
  unsigned o = (unsigned)f2b(v0) | ((unsigned)f2b(v1) << 16);
  *(unsigned*)&acc16[(size_t)d * 128 + c] = o;
}

// ---------------- FC (128x128) via MFMA + fused BN-stats ----------------
static __global__ __launch_bounds__(512)
void k_fc_mfma(const u16* __restrict__ A,      // [M][128] bf16
               const u16* __restrict__ Bt,     // [128][128] bf16 (row=outcol)
               const float* __restrict__ bias,
               float* __restrict__ Z, float* __restrict__ stats, int M)
{
  __shared__ u16 Ab[4][4096];   // 32 KB
  __shared__ float sst[256];

  const int row0 = blockIdx.x * 128;
  const int t    = threadIdx.x;
  const int lane = t & 63;
  const int w    = t >> 6;
  const int wm   = w >> 2;          // 0..1
  const int wn   = w & 3;           // 0..3
  const int l15  = lane & 15, l4 = lane >> 4;
  const int kl   = l4 * 8;

  if (t < 256) sst[t] = 0.f;

  int ar = row0 + w * 16 + l15;  if (ar >= M) ar = M - 1;

  bf16x8 br[2][4];
#pragma unroll
  for (int n = 0; n < 2; ++n)
#pragma unroll
    for (int ks = 0; ks < 4; ++ks)
      br[n][ks] = *(const bf16x8*)&Bt[(size_t)(wn * 32 + n * 16 + l15) * 128 + ks * 32 + kl];

#pragma unroll
  for (int ks = 0; ks < 4; ++ks)
    __builtin_amdgcn_global_load_lds(AS1(A + (size_t)ar * 128 + ks * 32 + kl),
                                     AS3(&Ab[ks][w * 512]), 16, 0, 0);

  asm volatile("s_waitcnt vmcnt(0)" ::: "memory");
  __syncthreads();

  f32x4 acc[4][2];
#pragma unroll
  for (int m = 0; m < 4; ++m) { acc[m][0] = (f32x4){0,0,0,0}; acc[m][1] = (f32x4){0,0,0,0}; }

#pragma unroll
  for (int ks = 0; ks < 4; ++ks) {
#pragma unroll
    for (int m = 0; m < 4; ++m) {
      bf16x8 a = *(const bf16x8*)&Ab[ks][(wm * 4 + m) * 512 + lane * 8];
      acc[m][0] = __builtin_amdgcn_mfma_f32_16x16x32_bf16(a, br[0][ks], acc[m][0], 0, 0, 0);
      acc[m][1] = __builtin_amdgcn_mfma_f32_16x16x32_bf16(a, br[1][ks], acc[m][1], 0, 0, 0);
    }
  }

  float ps[2] = {0.f, 0.f}, ps2[2] = {0.f, 0.f};
#pragma unroll
  for (int m = 0; m < 4; ++m) {
    const int rb = row0 + wm * 64 + m * 16 + l4 * 4;
#pragma unroll
    for (int j = 0; j < 4; ++j) {
      const int row = rb + j;
      const bool ok = row < M;
#pragma unroll
      for (int n = 0; n < 2; ++n) {
        const int cc = wn * 32 + n * 16 + l15;
        float v = ok ? fmaxf(acc[m][n][j] + bias[cc], 0.f) : 0.f;
        if (ok) Z[(size_t)row * 128 + cc] = v;
        ps[n]  += v;
        ps2[n] += v * v;
      }
    }
  }
#pragma unroll
  for (int n = 0; n < 2; ++n) {
    ps[n]  += __shfl_xor(ps[n], 16);  ps[n]  += __shfl_xor(ps[n], 32);
    ps2[n] += __shfl_xor(ps2[n], 16); ps2[n] += __shfl_xor(ps2[n], 32);
  }
  if (l4 == 0) {
#pragma unroll
    for (int n = 0; n < 2; ++n) {
      const int cc = wn * 32 + n * 16 + l15;
      atomicAdd(&sst[cc], ps[n]);
      atomicAdd(&sst[128 + cc], ps2[n]);
    }
  }
  __syncthreads();
  if (t < 256) atomicAdd(&stats[t], sst[t]);
}

// ---------------- BatchNorm finalize / final apply ----------------
static __global__ void k_bn_finalize(const float* __restrict__ stats, int M,
                                     const float* __restrict__ g, const float* __restrict__ beta,
                                     float* __restrict__ ab) {
  int j = threadIdx.x;  // 128
  float m  = stats[j] / (float)M;
  float v  = stats[128 + j] / (float)M - m * m;
  float inv = rsqrtf(v + EPSV) * g[j];
  ab[j]       = inv;
  ab[128 + j] = beta[j] - m * inv;
}

static __global__ void k_bn_apply_f32(const float* __restrict__ Z, const float* __restrict__ ab,
                                      float* __restrict__ out, int n) {
  int i = blockIdx.x * blockDim.x + threadIdx.x;
  if (i < n) {
    int j = i & 127;
    out[i] = Z[i] * ab[j] + ab[128 + j];
  }
}

extern "C" void kernel_launch(void* const* d_in, const int* in_sizes, int n_in,
                              void* d_out, int out_size, void* d_ws, size_t ws_size,
                              hipStream_t stream)
{
  const float* x    = (const float*)d_in[0];
  const int*   seq  = (const int*)d_in[1];
  const int*   knn  = (const int*)d_in[2];
  const int*   dis  = (const int*)d_in[3];
  const float* W0   = (const float*)d_in[4];
  const float* b0   = (const float*)d_in[5];
  const float* fcW0 = (const float*)d_in[6];
  const float* fcb0 = (const float*)d_in[7];
  const float* g0   = (const float*)d_in[8];
  const float* be0  = (const float*)d_in[9];
  const float* W1   = (const float*)d_in[10];
  const float* b1   = (const float*)d_in[11];
  const float* fcW1 = (const float*)d_in[12];
  const float* fcb1 = (const float*)d_in[13];
  const float* g1   = (const float*)d_in[14];
  const float* be1  = (const float*)d_in[15];

  const int E0 = in_sizes[1] / 2, E1 = in_sizes[2] / 2, E2 = in_sizes[3] / 2;
  const int ETOT = E0 + E1 + E2;

  const size_t N = NN;

  float* ws    = (float*)d_ws;
  float* sOut  = ws;                        // 3N raw out-degrees
  float* sIn   = sOut + 3 * N;              // 3N raw in-degrees
  u16*   acc16 = (u16*)(sIn + 3 * N);       // N*128 bf16
  float* stats = (float*)(acc16 + N * 128); // 512
  float* ab0   = stats + 512;               // 256
  float* ab1   = ab0 + 256;                 // 256
  u16*   Y     = (u16*)(ab1 + 256);         // N*384 bf16
  float* Z     = (float*)(Y + N * 384);     // N*128 f32
  u16*   Wt0   = (u16*)(Z + N * 128);       // 3*128*1280
  u16*   Wt1   = Wt0 + 3 * 128 * 1280;      // 3*128*128
  u16*   fcWt0 = Wt1 + 3 * 128 * 128;       // 128*128
  u16*   fcWt1 = fcWt0 + 128 * 128;         // 128*128
  int*   off   = (int*)(fcWt1 + 128 * 128); // N+1
  int*   aux   = off + (NN + 1);            // scan aux
  int*   cur   = aux + 1536;                // N
  int*   srt   = cur + NN;                  // ETOT

  const int NT = (NN + 127) / 128;

  // ---- preprocessing ----
  k_init<<<(6 * NN + 255) / 256, 256, 0, stream>>>(sOut, 6 * NN, cur, NN, stats, 512);
  k_deg_all<<<(ETOT + 255) / 256, 256, 0, stream>>>(seq, knn, dis, E0, E1, E2, sOut, sIn);

  const int nsc = NN + 1;
  const int nb  = (nsc + 255) / 256;
  k_scan1_c<<<nb, 256, 0, stream>>>(sIn, off, aux, nsc);
  k_scan2<<<1, 256, 0, stream>>>(aux, nb);
  k_scan3<<<nb, 256, 0, stream>>>(off, aux, nsc);

  k_fill_all<<<(ETOT + 255) / 256, 256, 0, stream>>>(seq, knn, dis, E0, E1, E2, off, cur, srt);

  const int CVT_TOT = 3 * 1280 * 128 + 3 * 128 * 128 + 2 * 128 * 128;
  k_cvt_all<<<(CVT_TOT + 255) / 256, 256, 0, stream>>>(W0, W1, fcW0, fcW1, Wt0, Wt1, fcWt0, fcWt1);

  // ---- layer 0 ----
  k_gemm_pipe<1280, false><<<NT, 1024, 0, stream>>>(x, Wt0, sOut, nullptr, Y, NN);
  k_gather<<<(NN + 3) / 4, 256, 0, stream>>>(off, srt, sIn, Y, b0, acc16);
  k_fc_mfma<<<NT, 512, 0, stream>>>(acc16, fcWt0, fcb0, Z, stats, NN);
  k_bn_finalize<<<1, 128, 0, stream>>>(stats, NN, g0, be0, ab0);

  // ---- layer 1 (BN-apply of layer 0 fused into gemm's cvt) ----
  k_gemm_pipe<128, true><<<NT, 1024, 0, stream>>>(Z, Wt1, sOut, ab0, Y, NN);
  k_gather<<<(NN + 3) / 4, 256, 0, stream>>>(off, srt, sIn, Y, b1, acc16);
  k_fc_mfma<<<NT, 512, 0, stream>>>(acc16, fcWt1, fcb1, Z, stats + 256, NN);
  k_bn_finalize<<<1, 128, 0, stream>>>(stats + 256, NN, g1, be1, ab1);
  k_bn_apply_f32<<<(NN * HID + 255) / 256, 256, 0, stream>>>(Z, ab1, (float*)d_out, NN * HID);
}